// Round 1
// baseline (157.722 us; speedup 1.0000x reference)
//
#include <hip/hip_runtime.h>

// Problem constants
#define TT    768     // tokens
#define K1    512     // 2*LDIMS (GEMM1 K)
#define HID_  512
#define NC    1024    // combined N (two halves)

__device__ __forceinline__ float fast_tanh(float x) {
    // tanh(x) = 1 - 2/(1+e^{2x}); e^{2x} = 2^(x*2/ln2)
#if __has_builtin(__builtin_amdgcn_exp2f)
    float e = __builtin_amdgcn_exp2f(x * 2.8853900817779268f);
#else
    float e = __expf(x * 2.0f);
#endif
#if __has_builtin(__builtin_amdgcn_rcpf)
    float r = __builtin_amdgcn_rcpf(e + 1.0f);
#else
    float r = 1.0f / (e + 1.0f);
#endif
    return fmaf(-2.0f, r, 1.0f);
}

// GEMM1: act[i][c] = tanh( xc[i][:] @ (c<512 ? FOH[:,c] : FOM[:,c-512]) + catBias[c] )
// M=768, N=1024, K=512. Tile 64x64, Kstep 16, 256 threads, 4x4 micro.
__global__ __launch_bounds__(256) void k_gemm1(
    const float* __restrict__ x, const float* __restrict__ foh,
    const float* __restrict__ fom, const float* __restrict__ catBias,
    float* __restrict__ act)
{
    __shared__ float As[16][68];  // [k][i], padded, rows 16B-aligned
    __shared__ float Bs[16][64];  // [k][n]
    const int t  = threadIdx.x;
    const int tx = t & 15, ty = t >> 4;
    const int n0 = blockIdx.x * 64;
    const int m0 = blockIdx.y * 64;
    const float* B = (n0 < 512) ? foh : fom;
    const int ncol0 = (n0 < 512) ? n0 : n0 - 512;

    const int ar = t >> 2;          // 0..63 tile row
    const int ak = (t & 3) * 4;     // k quad
    const int bk = t >> 4;          // 0..15 k
    const int bn = (t & 15) * 4;    // n quad

    float acc[4][4] = {};
    for (int kk = 0; kk < K1; kk += 16) {
        float4 av = *(const float4*)&x[(m0 + ar) * K1 + kk + ak];
        float4 bv = *(const float4*)&B[(kk + bk) * 512 + ncol0 + bn];
        __syncthreads();
        As[ak + 0][ar] = av.x;
        As[ak + 1][ar] = av.y;
        As[ak + 2][ar] = av.z;
        As[ak + 3][ar] = av.w;
        *(float4*)&Bs[bk][bn] = bv;
        __syncthreads();
        #pragma unroll
        for (int k = 0; k < 16; ++k) {
            float4 a4 = *(const float4*)&As[k][ty * 4];
            float4 b4 = *(const float4*)&Bs[k][tx * 4];
            float aa[4] = {a4.x, a4.y, a4.z, a4.w};
            float bb[4] = {b4.x, b4.y, b4.z, b4.w};
            #pragma unroll
            for (int i2 = 0; i2 < 4; ++i2)
                #pragma unroll
                for (int j2 = 0; j2 < 4; ++j2)
                    acc[i2][j2] = fmaf(aa[i2], bb[j2], acc[i2][j2]);
        }
    }
    #pragma unroll
    for (int i2 = 0; i2 < 4; ++i2) {
        int gi = m0 + ty * 4 + i2;
        #pragma unroll
        for (int j2 = 0; j2 < 4; ++j2) {
            int gc = n0 + tx * 4 + j2;
            float v = acc[i2][j2] + catBias[gc];
            act[gi * NC + gc] = fast_tanh(v);
        }
    }
}

// GEMM2: pw[i][c] =
//   c<512 : actH[i,:] @ hid2[0:512, c]   + hid2Bias[c]   (= AH + b2, "AHb")
//   c>=512: actM[i,:] @ hid2[512:1024, c-512]            (= AM)
__global__ __launch_bounds__(256) void k_gemm2(
    const float* __restrict__ act, const float* __restrict__ hid2,
    const float* __restrict__ hid2Bias, float* __restrict__ pw)
{
    __shared__ float As[16][68];
    __shared__ float Bs[16][64];
    const int t  = threadIdx.x;
    const int tx = t & 15, ty = t >> 4;
    const int n0 = blockIdx.x * 64;
    const int m0 = blockIdx.y * 64;
    const int koff  = (n0 < 512) ? 0 : 512;
    const int ncol0 = (n0 < 512) ? n0 : n0 - 512;

    const int ar = t >> 2;
    const int ak = (t & 3) * 4;
    const int bk = t >> 4;
    const int bn = (t & 15) * 4;

    float acc[4][4] = {};
    for (int kk = 0; kk < 512; kk += 16) {
        float4 av = *(const float4*)&act[(m0 + ar) * NC + koff + kk + ak];
        float4 bv = *(const float4*)&hid2[(koff + kk + bk) * 512 + ncol0 + bn];
        __syncthreads();
        As[ak + 0][ar] = av.x;
        As[ak + 1][ar] = av.y;
        As[ak + 2][ar] = av.z;
        As[ak + 3][ar] = av.w;
        *(float4*)&Bs[bk][bn] = bv;
        __syncthreads();
        #pragma unroll
        for (int k = 0; k < 16; ++k) {
            float4 a4 = *(const float4*)&As[k][ty * 4];
            float4 b4 = *(const float4*)&Bs[k][tx * 4];
            float aa[4] = {a4.x, a4.y, a4.z, a4.w};
            float bb[4] = {b4.x, b4.y, b4.z, b4.w};
            #pragma unroll
            for (int i2 = 0; i2 < 4; ++i2)
                #pragma unroll
                for (int j2 = 0; j2 < 4; ++j2)
                    acc[i2][j2] = fmaf(aa[i2], bb[j2], acc[i2][j2]);
        }
    }
    #pragma unroll
    for (int i2 = 0; i2 < 4; ++i2) {
        int gi = m0 + ty * 4 + i2;
        #pragma unroll
        for (int j2 = 0; j2 < 4; ++j2) {
            int gc = n0 + tx * 4 + j2;
            float v = acc[i2][j2];
            if (n0 < 512) v += hid2Bias[gc];
            pw[gi * NC + gc] = v;
        }
    }
}

// Pairwise: out[i][j] = outBias + sum_h w[h]*tanh(AHb[i,h] + AM[j,h])
// 32x32 (i,j) tile / block, 256 threads (16x16), 2x2 micro, h chunked by 64.
__global__ __launch_bounds__(256) void k_pair(
    const float* __restrict__ pw, const float* __restrict__ w,
    const float* __restrict__ outBias, float* __restrict__ out)
{
    __shared__ float Ach[32][68];
    __shared__ float Mch[32][68];
    __shared__ float wl[512];
    const int t  = threadIdx.x;
    const int tx = t & 15, ty = t >> 4;
    const int i0 = blockIdx.y * 32;
    const int j0 = blockIdx.x * 32;

    wl[t]       = w[t];
    wl[t + 256] = w[t + 256];

    const int sr = t >> 3;          // 0..31 row
    const int sc = (t & 7) * 8;     // 0..56, 8 floats per thread

    float acc[2][2] = {};
    for (int hh = 0; hh < 512; hh += 64) {
        float4 a0 = *(const float4*)&pw[(i0 + sr) * NC + hh + sc];
        float4 a1 = *(const float4*)&pw[(i0 + sr) * NC + hh + sc + 4];
        float4 m0 = *(const float4*)&pw[(j0 + sr) * NC + 512 + hh + sc];
        float4 m1 = *(const float4*)&pw[(j0 + sr) * NC + 512 + hh + sc + 4];
        __syncthreads();
        *(float4*)&Ach[sr][sc]     = a0;
        *(float4*)&Ach[sr][sc + 4] = a1;
        *(float4*)&Mch[sr][sc]     = m0;
        *(float4*)&Mch[sr][sc + 4] = m1;
        __syncthreads();
        #pragma unroll
        for (int h = 0; h < 64; h += 4) {
            float4 wa  = *(const float4*)&wl[hh + h];
            float4 va0 = *(const float4*)&Ach[ty][h];
            float4 va1 = *(const float4*)&Ach[ty + 16][h];
            float4 vm0 = *(const float4*)&Mch[tx][h];
            float4 vm1 = *(const float4*)&Mch[tx + 16][h];
            float wv[4] = {wa.x, wa.y, wa.z, wa.w};
            float A0[4] = {va0.x, va0.y, va0.z, va0.w};
            float A1[4] = {va1.x, va1.y, va1.z, va1.w};
            float M0[4] = {vm0.x, vm0.y, vm0.z, vm0.w};
            float M1[4] = {vm1.x, vm1.y, vm1.z, vm1.w};
            #pragma unroll
            for (int q = 0; q < 4; ++q) {
                acc[0][0] = fmaf(wv[q], fast_tanh(A0[q] + M0[q]), acc[0][0]);
                acc[0][1] = fmaf(wv[q], fast_tanh(A0[q] + M1[q]), acc[0][1]);
                acc[1][0] = fmaf(wv[q], fast_tanh(A1[q] + M0[q]), acc[1][0]);
                acc[1][1] = fmaf(wv[q], fast_tanh(A1[q] + M1[q]), acc[1][1]);
            }
        }
    }
    const float ob = outBias[0];
    out[(i0 + ty)      * TT + (j0 + tx)]      = acc[0][0] + ob;
    out[(i0 + ty)      * TT + (j0 + tx + 16)] = acc[0][1] + ob;
    out[(i0 + ty + 16) * TT + (j0 + tx)]      = acc[1][0] + ob;
    out[(i0 + ty + 16) * TT + (j0 + tx + 16)] = acc[1][1] + ob;
}

extern "C" void kernel_launch(void* const* d_in, const int* in_sizes, int n_in,
                              void* d_out, int out_size, void* d_ws, size_t ws_size,
                              hipStream_t stream) {
    const float* x        = (const float*)d_in[0];
    const float* foh      = (const float*)d_in[1];
    const float* fom      = (const float*)d_in[2];
    const float* catBias  = (const float*)d_in[3];
    const float* hid2     = (const float*)d_in[4];
    const float* hid2Bias = (const float*)d_in[5];
    const float* outLayer = (const float*)d_in[6];
    const float* outBias  = (const float*)d_in[7];
    float* out = (float*)d_out;

    float* act = (float*)d_ws;                 // [768][1024] actH|actM
    float* pw  = act + TT * NC;                // [768][1024] AHb|AM

    k_gemm1<<<dim3(NC / 64, TT / 64), 256, 0, stream>>>(x, foh, fom, catBias, act);
    k_gemm2<<<dim3(NC / 64, TT / 64), 256, 0, stream>>>(act, hid2, hid2Bias, pw);
    k_pair <<<dim3(TT / 32, TT / 32), 256, 0, stream>>>(pw, outLayer, outBias, out);
}

// Round 2
// 106.641 us; speedup vs baseline: 1.4790x; 1.4790x over previous
//
#include <hip/hip_runtime.h>

#define TT    768
#define KDIM  512
#define NC    1024
#define RLN2_2 2.8853900817779268f   // 2/ln(2)

__device__ __forceinline__ float fast_exp2(float x) {
#if __has_builtin(__builtin_amdgcn_exp2f)
    return __builtin_amdgcn_exp2f(x);
#else
    return exp2f(x);
#endif
}
__device__ __forceinline__ float fast_rcp(float x) {
#if __has_builtin(__builtin_amdgcn_rcpf)
    return __builtin_amdgcn_rcpf(x);
#else
    return 1.0f / x;
#endif
}
__device__ __forceinline__ float fast_tanh(float x) {
    float e = fast_exp2(x * RLN2_2);          // e^{2x}
    return fmaf(-2.0f, fast_rcp(e + 1.0f), 1.0f);
}

// ---------------------------------------------------------------------------
// GEMM1: act[i][c] = tanh( xc[i][:] @ (c<512 ? FOH : FOM)[:,c'] + catBias[c] )
// M=768, N=1024, K=512. Tile 48x64, 256 threads (16x16), micro 3x4.
// Grid = 16 x 16 = 256 blocks = exactly 1 per CU.
// ---------------------------------------------------------------------------
__global__ __launch_bounds__(256) void k_gemm1(
    const float* __restrict__ x, const float* __restrict__ foh,
    const float* __restrict__ fom, const float* __restrict__ catBias,
    float* __restrict__ act)
{
    __shared__ float As[16][52];   // [k][m], padded
    __shared__ float Bs[16][68];   // [k][n], padded
    const int t  = threadIdx.x;
    const int tx = t & 15, ty = t >> 4;
    const int n0 = blockIdx.x * 64;
    const int m0 = blockIdx.y * 48;
    const float* B = (n0 < 512) ? foh : fom;
    const int nc0  = (n0 < 512) ? n0 : n0 - 512;

    const int arow = t >> 2;          // 0..63 (only <48 used)
    const int akq  = (t & 3) * 4;
    const int bk   = t >> 4;          // 0..15
    const int bn   = (t & 15) * 4;

    float4 abuf = {}, bbuf;
    if (t < 192) abuf = *(const float4*)&x[(m0 + arow) * KDIM + akq];
    bbuf = *(const float4*)&B[bk * 512 + nc0 + bn];

    float acc[3][4] = {};
    for (int kk = 0; kk < KDIM; kk += 16) {
        __syncthreads();
        if (t < 192) {
            As[akq + 0][arow] = abuf.x; As[akq + 1][arow] = abuf.y;
            As[akq + 2][arow] = abuf.z; As[akq + 3][arow] = abuf.w;
        }
        *(float4*)&Bs[bk][bn] = bbuf;
        __syncthreads();
        if (kk + 16 < KDIM) {
            if (t < 192) abuf = *(const float4*)&x[(m0 + arow) * KDIM + kk + 16 + akq];
            bbuf = *(const float4*)&B[(kk + 16 + bk) * 512 + nc0 + bn];
        }
        #pragma unroll
        for (int k = 0; k < 16; ++k) {
            float a0 = As[k][ty * 3 + 0];
            float a1 = As[k][ty * 3 + 1];
            float a2 = As[k][ty * 3 + 2];
            float4 b4 = *(const float4*)&Bs[k][tx * 4];
            float bb[4] = {b4.x, b4.y, b4.z, b4.w};
            #pragma unroll
            for (int q = 0; q < 4; ++q) {
                acc[0][q] = fmaf(a0, bb[q], acc[0][q]);
                acc[1][q] = fmaf(a1, bb[q], acc[1][q]);
                acc[2][q] = fmaf(a2, bb[q], acc[2][q]);
            }
        }
    }
    float4 cb = *(const float4*)&catBias[n0 + tx * 4];
    float cbv[4] = {cb.x, cb.y, cb.z, cb.w};
    #pragma unroll
    for (int d = 0; d < 3; ++d) {
        int row = m0 + ty * 3 + d;
        float4 o;
        o.x = fast_tanh(acc[d][0] + cbv[0]);
        o.y = fast_tanh(acc[d][1] + cbv[1]);
        o.z = fast_tanh(acc[d][2] + cbv[2]);
        o.w = fast_tanh(acc[d][3] + cbv[3]);
        *(float4*)&act[row * NC + n0 + tx * 4] = o;
    }
}

// ---------------------------------------------------------------------------
// GEMM2 + exp epilogue:
//   c<512 : EA[i][c] = exp2( c2 * (actH@hid2top + hid2Bias)[i][c] )
//   c>=512: EM[i][c'] = exp2( c2 * (actM@hid2bot)[i][c'] )
// Same tiling as GEMM1.
// ---------------------------------------------------------------------------
__global__ __launch_bounds__(256) void k_gemm2(
    const float* __restrict__ act, const float* __restrict__ hid2,
    const float* __restrict__ hid2Bias, float* __restrict__ pw)
{
    __shared__ float As[16][52];
    __shared__ float Bs[16][68];
    const int t  = threadIdx.x;
    const int tx = t & 15, ty = t >> 4;
    const int n0 = blockIdx.x * 64;
    const int m0 = blockIdx.y * 48;
    const int koff = (n0 < 512) ? 0 : 512;
    const int nc0  = (n0 < 512) ? n0 : n0 - 512;

    const int arow = t >> 2;
    const int akq  = (t & 3) * 4;
    const int bk   = t >> 4;
    const int bn   = (t & 15) * 4;

    float4 abuf = {}, bbuf;
    if (t < 192) abuf = *(const float4*)&act[(m0 + arow) * NC + koff + akq];
    bbuf = *(const float4*)&hid2[(koff + bk) * 512 + nc0 + bn];

    float acc[3][4] = {};
    for (int kk = 0; kk < 512; kk += 16) {
        __syncthreads();
        if (t < 192) {
            As[akq + 0][arow] = abuf.x; As[akq + 1][arow] = abuf.y;
            As[akq + 2][arow] = abuf.z; As[akq + 3][arow] = abuf.w;
        }
        *(float4*)&Bs[bk][bn] = bbuf;
        __syncthreads();
        if (kk + 16 < 512) {
            if (t < 192) abuf = *(const float4*)&act[(m0 + arow) * NC + koff + kk + 16 + akq];
            bbuf = *(const float4*)&hid2[(koff + kk + 16 + bk) * 512 + nc0 + bn];
        }
        #pragma unroll
        for (int k = 0; k < 16; ++k) {
            float a0 = As[k][ty * 3 + 0];
            float a1 = As[k][ty * 3 + 1];
            float a2 = As[k][ty * 3 + 2];
            float4 b4 = *(const float4*)&Bs[k][tx * 4];
            float bb[4] = {b4.x, b4.y, b4.z, b4.w};
            #pragma unroll
            for (int q = 0; q < 4; ++q) {
                acc[0][q] = fmaf(a0, bb[q], acc[0][q]);
                acc[1][q] = fmaf(a1, bb[q], acc[1][q]);
                acc[2][q] = fmaf(a2, bb[q], acc[2][q]);
            }
        }
    }
    float bv[4] = {0.f, 0.f, 0.f, 0.f};
    if (n0 < 512) {
        float4 b4 = *(const float4*)&hid2Bias[n0 + tx * 4];
        bv[0] = b4.x; bv[1] = b4.y; bv[2] = b4.z; bv[3] = b4.w;
    }
    #pragma unroll
    for (int d = 0; d < 3; ++d) {
        int row = m0 + ty * 3 + d;
        float4 o;
        o.x = fast_exp2(RLN2_2 * (acc[d][0] + bv[0]));
        o.y = fast_exp2(RLN2_2 * (acc[d][1] + bv[1]));
        o.z = fast_exp2(RLN2_2 * (acc[d][2] + bv[2]));
        o.w = fast_exp2(RLN2_2 * (acc[d][3] + bv[3]));
        *(float4*)&pw[row * NC + n0 + tx * 4] = o;
    }
}

// ---------------------------------------------------------------------------
// Pairwise: out[i][j] = outBias + sum_h w[h] * tanh(A[i,h]+M[j,h])
//   with EA=e^{2A}, EM=e^{2M}:  tanh = 1 - 2/(1 + EA*EM)
//   out = outBias + sum(w) - 2 * sum_h w[h] / fma(EA,EM,1)
// 16x16 tile per 1-wave block, 2x2 micro. Grid = 2304 = 9 waves/CU exactly.
// ---------------------------------------------------------------------------
__global__ __launch_bounds__(64) void k_pair(
    const float* __restrict__ pw, const float* __restrict__ w,
    const float* __restrict__ outBias, float* __restrict__ out)
{
    __shared__ float Ea[16][68];
    __shared__ float Em[16][68];
    const int t   = threadIdx.x;              // 0..63
    const int bid = blockIdx.x;
    // XCD-aware swizzle: XCD k gets orig tiles [k*288, (k+1)*288) -> 6 i-rows
    const int sw = (bid & 7) * 288 + (bid >> 3);
    const int it = sw / 48, jt = sw % 48;
    const int i0 = it * 16, j0 = jt * 16;
    const int ti = t >> 3, tj = t & 7;

    // staging: 4 float4 per array per thread; q -> rows 4q..4q+3
    const int srow[4] = { (0 * 64 + t) >> 4, (1 * 64 + t) >> 4,
                          (2 * 64 + t) >> 4, (3 * 64 + t) >> 4 };
    const int scol = (t & 15) * 4;

    float4 ab[4], mb[4];
    #pragma unroll
    for (int q = 0; q < 4; ++q) {
        ab[q] = *(const float4*)&pw[(i0 + srow[q]) * NC + scol];
        mb[q] = *(const float4*)&pw[(j0 + srow[q]) * NC + 512 + scol];
    }

    float acc00 = 0.f, acc01 = 0.f, acc10 = 0.f, acc11 = 0.f;
    float wsum = 0.f;

    for (int c = 0; c < 8; ++c) {
        const int hh = c * 64;
        __syncthreads();
        #pragma unroll
        for (int q = 0; q < 4; ++q) {
            *(float4*)&Ea[srow[q]][scol] = ab[q];
            *(float4*)&Em[srow[q]][scol] = mb[q];
        }
        __syncthreads();
        if (c < 7) {
            const int hn = hh + 64;
            #pragma unroll
            for (int q = 0; q < 4; ++q) {
                ab[q] = *(const float4*)&pw[(i0 + srow[q]) * NC + hn + scol];
                mb[q] = *(const float4*)&pw[(j0 + srow[q]) * NC + 512 + hn + scol];
            }
        }
        #pragma unroll 8
        for (int hq = 0; hq < 16; ++hq) {
            const int h = hq * 4;
            float4 e0 = *(const float4*)&Ea[2 * ti][h];
            float4 e1 = *(const float4*)&Ea[2 * ti + 1][h];
            float4 f0 = *(const float4*)&Em[2 * tj][h];
            float4 f1 = *(const float4*)&Em[2 * tj + 1][h];
            float4 w4 = *(const float4*)&w[hh + h];
            float ee0[4] = {e0.x, e0.y, e0.z, e0.w};
            float ee1[4] = {e1.x, e1.y, e1.z, e1.w};
            float ff0[4] = {f0.x, f0.y, f0.z, f0.w};
            float ff1[4] = {f1.x, f1.y, f1.z, f1.w};
            float ww[4]  = {w4.x, w4.y, w4.z, w4.w};
            wsum += (w4.x + w4.y) + (w4.z + w4.w);
            #pragma unroll
            for (int q = 0; q < 4; ++q) {
                acc00 = fmaf(ww[q], fast_rcp(fmaf(ee0[q], ff0[q], 1.0f)), acc00);
                acc01 = fmaf(ww[q], fast_rcp(fmaf(ee0[q], ff1[q], 1.0f)), acc01);
                acc10 = fmaf(ww[q], fast_rcp(fmaf(ee1[q], ff0[q], 1.0f)), acc10);
                acc11 = fmaf(ww[q], fast_rcp(fmaf(ee1[q], ff1[q], 1.0f)), acc11);
            }
        }
    }
    const float base = wsum + outBias[0];
    const int gi = i0 + 2 * ti, gj = j0 + 2 * tj;
    float2 r0, r1;
    r0.x = fmaf(-2.0f, acc00, base);
    r0.y = fmaf(-2.0f, acc01, base);
    r1.x = fmaf(-2.0f, acc10, base);
    r1.y = fmaf(-2.0f, acc11, base);
    *(float2*)&out[gi * TT + gj]       = r0;
    *(float2*)&out[(gi + 1) * TT + gj] = r1;
}

extern "C" void kernel_launch(void* const* d_in, const int* in_sizes, int n_in,
                              void* d_out, int out_size, void* d_ws, size_t ws_size,
                              hipStream_t stream) {
    const float* x        = (const float*)d_in[0];
    const float* foh      = (const float*)d_in[1];
    const float* fom      = (const float*)d_in[2];
    const float* catBias  = (const float*)d_in[3];
    const float* hid2     = (const float*)d_in[4];
    const float* hid2Bias = (const float*)d_in[5];
    const float* outLayer = (const float*)d_in[6];
    const float* outBias  = (const float*)d_in[7];
    float* out = (float*)d_out;

    float* act = (float*)d_ws;            // [768][1024]
    float* pw  = act + TT * NC;           // [768][1024] EA|EM

    k_gemm1<<<dim3(NC / 64, TT / 48), 256, 0, stream>>>(x, foh, fom, catBias, act);
    k_gemm2<<<dim3(NC / 64, TT / 48), 256, 0, stream>>>(act, hid2, hid2Bias, pw);
    k_pair <<<dim3(2304), 64, 0, stream>>>(pw, outLayer, outBias, out);
}

// Round 3
// 86.074 us; speedup vs baseline: 1.8324x; 1.2389x over previous
//
#include <hip/hip_runtime.h>

#define TT 768
#define KD 512
#define NC 1024
#define RLN2_2 2.8853900817779268f   // 2/ln(2)

typedef short short8 __attribute__((ext_vector_type(8)));
typedef float f32x4  __attribute__((ext_vector_type(4)));

__device__ __forceinline__ float fast_exp2(float x) {
#if __has_builtin(__builtin_amdgcn_exp2f)
    return __builtin_amdgcn_exp2f(x);
#else
    return exp2f(x);
#endif
}
__device__ __forceinline__ float fast_rcp(float x) {
#if __has_builtin(__builtin_amdgcn_rcpf)
    return __builtin_amdgcn_rcpf(x);
#else
    return 1.0f / x;
#endif
}
__device__ __forceinline__ float fast_tanh(float x) {
    float e = fast_exp2(x * RLN2_2);
    return fmaf(-2.0f, fast_rcp(e + 1.0f), 1.0f);
}
__device__ __forceinline__ ushort f2bf(float f) {   // RNE f32->bf16
    uint u = __float_as_uint(f);
    u += 0x7fff + ((u >> 16) & 1);
    return (ushort)(u >> 16);
}

// ---------------------------------------------------------------------------
// Prep: blocks 0..95   : x f32 -> xb bf16 (768x512)
//       blocks 96..159 : foh [512][512] -> b1t rows 0..511   ([c][k] bf16)
//       blocks 160..223: fom [512][512] -> b1t rows 512..1023
//       blocks 224..351: hid2 [1024][512] -> h2t [512][1024] ([n][k] bf16)
// ---------------------------------------------------------------------------
__global__ __launch_bounds__(256) void k_prep(
    const float* __restrict__ x, const float* __restrict__ foh,
    const float* __restrict__ fom, const float* __restrict__ hid2,
    ushort* __restrict__ xb, ushort* __restrict__ b1t, ushort* __restrict__ h2t)
{
    const int b = blockIdx.x, t = threadIdx.x;
    if (b < 96) {
        int base = b * 4096 + t * 16;
        #pragma unroll
        for (int q = 0; q < 4; ++q) {
            float4 v = *(const float4*)&x[base + q * 4];
            ushort4 o; o.x = f2bf(v.x); o.y = f2bf(v.y); o.z = f2bf(v.z); o.w = f2bf(v.w);
            *(ushort4*)&xb[base + q * 4] = o;
        }
        return;
    }
    __shared__ float tile[64][65];
    const float* src; ushort* dst; int R, C, r0, c0;
    if (b < 160)      { int bb = b - 96;  src = foh;  dst = b1t;             R = 512;  C = 512; r0 = (bb >> 3) * 64; c0 = (bb & 7) * 64; }
    else if (b < 224) { int bb = b - 160; src = fom;  dst = b1t + 512 * 512; R = 512;  C = 512; r0 = (bb >> 3) * 64; c0 = (bb & 7) * 64; }
    else              { int bb = b - 224; src = hid2; dst = h2t;             R = 1024; C = 512; r0 = (bb >> 3) * 64; c0 = (bb & 7) * 64; }
    const int ty = t >> 4, tx = t & 15;
    #pragma unroll
    for (int q = 0; q < 4; ++q) {
        float4 v = *(const float4*)&src[(r0 + ty + q * 16) * C + c0 + tx * 4];
        tile[ty + q * 16][tx * 4 + 0] = v.x;
        tile[ty + q * 16][tx * 4 + 1] = v.y;
        tile[ty + q * 16][tx * 4 + 2] = v.z;
        tile[ty + q * 16][tx * 4 + 3] = v.w;
    }
    __syncthreads();
    #pragma unroll
    for (int q = 0; q < 4; ++q) {
        int cl = ty + q * 16;
        ushort4 o;
        o.x = f2bf(tile[tx * 4 + 0][cl]);
        o.y = f2bf(tile[tx * 4 + 1][cl]);
        o.z = f2bf(tile[tx * 4 + 2][cl]);
        o.w = f2bf(tile[tx * 4 + 3][cl]);
        *(ushort4*)&dst[(c0 + cl) * R + r0 + tx * 4] = o;
    }
}

// ---------------------------------------------------------------------------
// GEMM1 (MFMA bf16): act[i][c] = tanh( xb[i,:] . b1t[c,:] + catBias[c] ) bf16
// Block 256thr = 4 waves (2x2), wave = 32x32 out (2x2 16x16x32 frags).
// A,B fragments loaded directly from global (L2-resident), no LDS.
// ---------------------------------------------------------------------------
__global__ __launch_bounds__(256) void k_gemm1(
    const ushort* __restrict__ xb, const ushort* __restrict__ b1t,
    const float* __restrict__ catBias, ushort* __restrict__ act)
{
    const int t = threadIdx.x;
    const int wave = t >> 6, lane = t & 63;
    const int wr = wave >> 1, wc = wave & 1;
    const int n0 = blockIdx.x * 64 + wc * 32;
    const int m0 = blockIdx.y * 64 + wr * 32;
    const int lrow = lane & 15, lk = (lane >> 4) * 8;

    const ushort* pa0 = &xb[(m0 + lrow) * KD + lk];
    const ushort* pa1 = pa0 + 16 * KD;
    const ushort* pb0 = &b1t[(n0 + lrow) * KD + lk];
    const ushort* pb1 = pb0 + 16 * KD;

    f32x4 acc[2][2] = {};
    #pragma unroll 4
    for (int k0 = 0; k0 < KD; k0 += 32) {
        short8 a0 = *(const short8*)(pa0 + k0);
        short8 a1 = *(const short8*)(pa1 + k0);
        short8 b0 = *(const short8*)(pb0 + k0);
        short8 b1 = *(const short8*)(pb1 + k0);
        acc[0][0] = __builtin_amdgcn_mfma_f32_16x16x32_bf16(a0, b0, acc[0][0], 0, 0, 0);
        acc[0][1] = __builtin_amdgcn_mfma_f32_16x16x32_bf16(a0, b1, acc[0][1], 0, 0, 0);
        acc[1][0] = __builtin_amdgcn_mfma_f32_16x16x32_bf16(a1, b0, acc[1][0], 0, 0, 0);
        acc[1][1] = __builtin_amdgcn_mfma_f32_16x16x32_bf16(a1, b1, acc[1][1], 0, 0, 0);
    }
    const int crow = (lane >> 4) * 4, ccol = lane & 15;
    #pragma unroll
    for (int nf = 0; nf < 2; ++nf) {
        int col = n0 + nf * 16 + ccol;
        float cb = catBias[col];
        #pragma unroll
        for (int mf = 0; mf < 2; ++mf) {
            #pragma unroll
            for (int r = 0; r < 4; ++r) {
                int row = m0 + mf * 16 + crow + r;
                act[row * NC + col] = f2bf(fast_tanh(acc[mf][nf][r] + cb));
            }
        }
    }
}

// ---------------------------------------------------------------------------
// GEMM2 (MFMA bf16) + exp epilogue:
//   c<512 : pw[i][c] = exp2(RLN2_2*(actH[i,:].h2t[c,:]+hid2Bias[c]))
//   c>=512: pw[i][c] = exp2(RLN2_2*(actM[i,:].h2t[c-512, 512:]))
// ---------------------------------------------------------------------------
__global__ __launch_bounds__(256) void k_gemm2(
    const ushort* __restrict__ act, const ushort* __restrict__ h2t,
    const float* __restrict__ hid2Bias, float* __restrict__ pw)
{
    const int t = threadIdx.x;
    const int wave = t >> 6, lane = t & 63;
    const int wr = wave >> 1, wc = wave & 1;
    const int n0 = blockIdx.x * 64 + wc * 32;
    const int m0 = blockIdx.y * 64 + wr * 32;
    const bool top = (blockIdx.x < 8);
    const int koff = top ? 0 : 512;
    const int nc0  = top ? n0 : n0 - 512;
    const int lrow = lane & 15, lk = (lane >> 4) * 8;

    const ushort* pa0 = &act[(m0 + lrow) * NC + koff + lk];
    const ushort* pa1 = pa0 + 16 * NC;
    const ushort* pb0 = &h2t[(nc0 + lrow) * NC + koff + lk];
    const ushort* pb1 = pb0 + 16 * NC;

    f32x4 acc[2][2] = {};
    #pragma unroll 4
    for (int k0 = 0; k0 < KD; k0 += 32) {
        short8 a0 = *(const short8*)(pa0 + k0);
        short8 a1 = *(const short8*)(pa1 + k0);
        short8 b0 = *(const short8*)(pb0 + k0);
        short8 b1 = *(const short8*)(pb1 + k0);
        acc[0][0] = __builtin_amdgcn_mfma_f32_16x16x32_bf16(a0, b0, acc[0][0], 0, 0, 0);
        acc[0][1] = __builtin_amdgcn_mfma_f32_16x16x32_bf16(a0, b1, acc[0][1], 0, 0, 0);
        acc[1][0] = __builtin_amdgcn_mfma_f32_16x16x32_bf16(a1, b0, acc[1][0], 0, 0, 0);
        acc[1][1] = __builtin_amdgcn_mfma_f32_16x16x32_bf16(a1, b1, acc[1][1], 0, 0, 0);
    }
    const int crow = (lane >> 4) * 4, ccol = lane & 15;
    #pragma unroll
    for (int nf = 0; nf < 2; ++nf) {
        int col = n0 + nf * 16 + ccol;
        float hb = top ? hid2Bias[col] : 0.0f;
        #pragma unroll
        for (int mf = 0; mf < 2; ++mf) {
            #pragma unroll
            for (int r = 0; r < 4; ++r) {
                int row = m0 + mf * 16 + crow + r;
                pw[row * NC + col] = fast_exp2(RLN2_2 * (acc[mf][nf][r] + hb));
            }
        }
    }
}

// ---------------------------------------------------------------------------
// Pairwise: out[i][j] = (outBias + sum w) - 2*sum_h w[h]/fma(EA,EM,1)
// 16x16 tile per 1-wave block, 2x2 micro. Grid = 2304 = 9 waves/CU.
// w staged in LDS once; sum(w) via butterfly shuffle (no in-loop globals).
// ---------------------------------------------------------------------------
__global__ __launch_bounds__(64) void k_pair(
    const float* __restrict__ pw, const float* __restrict__ w,
    const float* __restrict__ outBias, float* __restrict__ out)
{
    __shared__ float Ea[16][68];
    __shared__ float Em[16][68];
    __shared__ float wl[512];
    const int t   = threadIdx.x;
    const int bid = blockIdx.x;
    const int sw  = (bid & 7) * 288 + (bid >> 3);   // XCD swizzle (2304%8==0)
    const int it = sw / 48, jt = sw % 48;
    const int i0 = it * 16, j0 = jt * 16;
    const int ti = t >> 3, tj = t & 7;

    float lsum = 0.f;
    #pragma unroll
    for (int q = 0; q < 8; ++q) {
        float v = w[q * 64 + t];
        wl[q * 64 + t] = v;
        lsum += v;
    }
    #pragma unroll
    for (int d = 1; d < 64; d <<= 1) lsum += __shfl_xor(lsum, d, 64);

    const int srow[4] = { (0 * 64 + t) >> 4, (1 * 64 + t) >> 4,
                          (2 * 64 + t) >> 4, (3 * 64 + t) >> 4 };
    const int scol = (t & 15) * 4;

    float4 ab[4], mb[4];
    #pragma unroll
    for (int q = 0; q < 4; ++q) {
        ab[q] = *(const float4*)&pw[(i0 + srow[q]) * NC + scol];
        mb[q] = *(const float4*)&pw[(j0 + srow[q]) * NC + 512 + scol];
    }

    float acc00 = 0.f, acc01 = 0.f, acc10 = 0.f, acc11 = 0.f;

    for (int c = 0; c < 8; ++c) {
        const int hh = c * 64;
        __syncthreads();
        #pragma unroll
        for (int q = 0; q < 4; ++q) {
            *(float4*)&Ea[srow[q]][scol] = ab[q];
            *(float4*)&Em[srow[q]][scol] = mb[q];
        }
        __syncthreads();
        if (c < 7) {
            const int hn = hh + 64;
            #pragma unroll
            for (int q = 0; q < 4; ++q) {
                ab[q] = *(const float4*)&pw[(i0 + srow[q]) * NC + hn + scol];
                mb[q] = *(const float4*)&pw[(j0 + srow[q]) * NC + 512 + hn + scol];
            }
        }
        #pragma unroll 16
        for (int hq = 0; hq < 16; ++hq) {
            const int h = hq * 4;
            float4 e0 = *(const float4*)&Ea[2 * ti][h];
            float4 e1 = *(const float4*)&Ea[2 * ti + 1][h];
            float4 f0 = *(const float4*)&Em[2 * tj][h];
            float4 f1 = *(const float4*)&Em[2 * tj + 1][h];
            float4 w4 = *(const float4*)&wl[hh + h];
            float ee0[4] = {e0.x, e0.y, e0.z, e0.w};
            float ee1[4] = {e1.x, e1.y, e1.z, e1.w};
            float ff0[4] = {f0.x, f0.y, f0.z, f0.w};
            float ff1[4] = {f1.x, f1.y, f1.z, f1.w};
            float ww[4]  = {w4.x, w4.y, w4.z, w4.w};
            #pragma unroll
            for (int q = 0; q < 4; ++q) {
                acc00 = fmaf(ww[q], fast_rcp(fmaf(ee0[q], ff0[q], 1.0f)), acc00);
                acc01 = fmaf(ww[q], fast_rcp(fmaf(ee0[q], ff1[q], 1.0f)), acc01);
                acc10 = fmaf(ww[q], fast_rcp(fmaf(ee1[q], ff0[q], 1.0f)), acc10);
                acc11 = fmaf(ww[q], fast_rcp(fmaf(ee1[q], ff1[q], 1.0f)), acc11);
            }
        }
    }
    const float base = lsum + outBias[0];
    const int gi = i0 + 2 * ti, gj = j0 + 2 * tj;
    float2 r0, r1;
    r0.x = fmaf(-2.0f, acc00, base);
    r0.y = fmaf(-2.0f, acc01, base);
    r1.x = fmaf(-2.0f, acc10, base);
    r1.y = fmaf(-2.0f, acc11, base);
    *(float2*)&out[gi * TT + gj]       = r0;
    *(float2*)&out[(gi + 1) * TT + gj] = r1;
}

extern "C" void kernel_launch(void* const* d_in, const int* in_sizes, int n_in,
                              void* d_out, int out_size, void* d_ws, size_t ws_size,
                              hipStream_t stream) {
    const float* x        = (const float*)d_in[0];
    const float* foh      = (const float*)d_in[1];
    const float* fom      = (const float*)d_in[2];
    const float* catBias  = (const float*)d_in[3];
    const float* hid2     = (const float*)d_in[4];
    const float* hid2Bias = (const float*)d_in[5];
    const float* outLayer = (const float*)d_in[6];
    const float* outBias  = (const float*)d_in[7];
    float* out = (float*)d_out;

    char* wsb = (char*)d_ws;
    float*  pw  = (float*)(wsb);                        // 768*1024*4 = 3145728
    ushort* act = (ushort*)(wsb + 3145728);             // 768*1024*2 = 1572864
    ushort* xb  = (ushort*)(wsb + 4718592);             // 768*512*2  = 786432
    ushort* b1t = (ushort*)(wsb + 5505024);             // 1024*512*2 = 1048576
    ushort* h2t = (ushort*)(wsb + 6553600);             // 512*1024*2 = 1048576

    k_prep <<<dim3(352),        256, 0, stream>>>(x, foh, fom, hid2, xb, b1t, h2t);
    k_gemm1<<<dim3(16, 12),     256, 0, stream>>>(xb, b1t, catBias, act);
    k_gemm2<<<dim3(16, 12),     256, 0, stream>>>(act, h2t, hid2Bias, pw);
    k_pair <<<dim3(2304),        64, 0, stream>>>(pw, outLayer, outBias, out);
}